// Round 4
// baseline (6095.291 us; speedup 1.0000x reference)
//
#include <hip/hip_runtime.h>

#define SEQ  128
#define B_   512
#define NKT  24

typedef _Float16 f16;
typedef _Float16 f16x8 __attribute__((ext_vector_type(8)));
typedef float    f32x4  __attribute__((ext_vector_type(4)));
typedef float    f32x16 __attribute__((ext_vector_type(16)));

// ws layout (bytes)
#define OFF_BT   0u          // [4096][1024] f16 (r<512: Wih, r>=512: Whh)
#define OFF_X16  8388608u    // [128][512][512] f16
#define OFF_MH   75497472u   // [2][262144] f16
#define OFF_ML   76546048u   // [2][262144] f16
#define OFF_C    77594624u   // [512][512] f32 (tier-3 only)
#define OFF_BAR  78643200u   // u32 arrival counter

__device__ __forceinline__ void gll16(const void* g, void* l) {
  __builtin_amdgcn_global_load_lds(
      (const __attribute__((address_space(1))) unsigned int*)g,
      (__attribute__((address_space(3))) unsigned int*)l, 16, 0, 0);
}
__device__ __forceinline__ float sigm_f(float x) {
  return __fdividef(1.f, 1.f + __expf(-x));
}
__device__ __forceinline__ float tanh_f(float x) {
  x = fminf(fmaxf(x, -15.f), 15.f);
  float u = __expf(2.f * x);
  return __fdividef(u - 1.f, u + 1.f);
}
#define VW(n) asm volatile("s_waitcnt vmcnt(" #n ")" ::: "memory")

// ---- one-time prep --------------------------------------------------------
__global__ void build_bt(const float* __restrict__ wih,
                         const float* __restrict__ whh,
                         f16* __restrict__ bt) {
  int n  = blockIdx.x;                 // n = ht*128 + gate*16 + hl
  int hl = n & 15, k = (n >> 4) & 7, ht = n >> 7;
  int h  = ht * 16 + hl;
  const float* pih = wih + (size_t)k * 512 * 512 + h;
  const float* phh = whh + (size_t)k * 512 * 512 + h;
  f16* dst = bt + (size_t)n * 1024;
  for (int r = threadIdx.x; r < 512; r += 256) {
    dst[r]       = (f16)pih[(size_t)r * 512];
    dst[512 + r] = (f16)phh[(size_t)r * 512];
  }
}

__global__ void cvt_x(const float4* __restrict__ x, f16* __restrict__ y, int nvec) {
  typedef _Float16 f16x4v __attribute__((ext_vector_type(4)));
  int i = blockIdx.x * blockDim.x + threadIdx.x;
  int stride = gridDim.x * blockDim.x;
  f16x4v* yo = (f16x4v*)y;
  for (; i < nvec; i += stride) {
    float4 v = x[i];
    f16x4v o = { (f16)v.x, (f16)v.y, (f16)v.z, (f16)v.w };
    yo[i] = o;
  }
}

__global__ void init_state(f16* __restrict__ mh, f16* __restrict__ ml,
                           float* __restrict__ c, unsigned int* __restrict__ bar) {
  int i = blockIdx.x * blockDim.x + threadIdx.x;
  mh[i] = (f16)1.f;
  ml[i] = (f16)0.f;
  c[i]  = 1.f;
  if (i == 0) *bar = 0u;
}

// ---- tier 1/2: persistent, B-in-registers ---------------------------------
// grid 256 (nt = bid&31, mt = bid>>5), 512 threads = 8 waves.
// wave wid: kg = wid>>2 (K-half), ni = wid&3 (32 N-cols). Wave tile 64Mx32N,
// MFMA 32x32x16. B resident: 32 x f16x8 = 128 VGPR/lane, loaded once.
// Per step: 12 superphases; sp s: src = s>>2 (x,mh,ml), jj = s&3; two A-tiles
// [64M][64K] (one per kg) in a 6-slot LDS ring, staged 2 sps ahead, VW(2).
// ml superphases reuse mh's Whh B-fragments (same registers, free).
__global__ __launch_bounds__(512, 2)
void nas_persist2(const f16* __restrict__ X, const f16* __restrict__ BT,
                  f16* __restrict__ MHb, f16* __restrict__ MLb,
                  unsigned int* __restrict__ bar, float* __restrict__ out) {
  __shared__ char lds[114688];               // 6x8KB A-slots | 64KB acc buffer
  float* accf = (float*)(lds + 49152);
  const int tid  = threadIdx.x;
  const int lane = tid & 63;
  const int wid  = tid >> 6;
  const int kg   = wid >> 2;
  const int ni   = wid & 3;
  const int nt   = blockIdx.x & 31;
  const int mt   = blockIdx.x >> 5;

  // ---- B prologue: lane's 32 fragments (col c -> n = nt*128+(c>>2)*16+ni*4+(c&3))
  f16x8 bfrag[32];
  {
    int c = lane & 31;
    int nrow = nt * 128 + (c >> 2) * 16 + ni * 4 + (c & 3);
    const f16* bb = BT + (size_t)nrow * 1024 + (lane >> 5) * 8 + kg * 256;
#pragma unroll
    for (int f = 0; f < 16; ++f)           // Wih half
      bfrag[f] = *(const f16x8*)(bb + (f >> 2) * 64 + (f & 3) * 16);
#pragma unroll
    for (int f = 0; f < 16; ++f)           // Whh half (shared by mh and ml)
      bfrag[16 + f] = *(const f16x8*)(bb + 512 + (f >> 2) * 64 + (f & 3) * 16);
  }

  // stage A-tile for (step ti, superphase spe, tile-kg): 1 gll16/thread.
  // logical (r,c16) at phys r*128 + 16*(c16 ^ (r&7)) -> pre-swizzled source.
  auto stage = [&](int ti, int spe, int tkg) {
    int src = spe >> 2, jj = spe & 3;
    const f16* base = (src == 0) ? X + (size_t)ti * 262144
                    : (src == 1) ? MHb + (size_t)(ti & 1) * 262144
                                 : MLb + (size_t)(ti & 1) * 262144;
    int col0 = tkg * 256 + jj * 64;
    int r = tid >> 3;
    int c = (tid & 7) ^ (r & 7);
    char* dst = lds + ((2 * spe + tkg) % 6) * 8192 + wid * 1024;  // wave-uniform
    gll16(base + ((size_t)(mt * 64 + r) << 9) + col0 + c * 8, dst);
  };

  f32x16 acc[2];
  float creg[2];
  creg[0] = 1.f; creg[1] = 1.f;

  stage(0, 0, 0); stage(0, 0, 1); stage(0, 1, 0); stage(0, 1, 1);   // prologue

  for (int t = 0; t < SEQ; ++t) {
#pragma unroll
    for (int mi = 0; mi < 2; ++mi) {
      f32x16 z = {0.f,0.f,0.f,0.f,0.f,0.f,0.f,0.f,
                  0.f,0.f,0.f,0.f,0.f,0.f,0.f,0.f};
      acc[mi] = z;
    }

#pragma unroll
    for (int s = 0; s < 12; ++s) {
      VW(2);                                  // tiles of sp s complete
      __builtin_amdgcn_s_barrier();
      asm volatile("" ::: "memory");

      if (s == 2 && t > 0) {                  // gate before first m-tile staging
        if (tid == 0) {
          while (__hip_atomic_load(bar, __ATOMIC_RELAXED,
                                   __HIP_MEMORY_SCOPE_AGENT) < (unsigned)(256u * t))
            __builtin_amdgcn_s_sleep(2);
          __builtin_amdgcn_fence(__ATOMIC_ACQUIRE, "agent");
        }
        __builtin_amdgcn_s_barrier();
      }

      { // issue stage for sp s+2 (wraps to next step's x-phases)
        int sp2 = s + 2, ti = t;
        if (sp2 >= 12) { sp2 -= 12; ti = (t + 1 < SEQ) ? t + 1 : t; }
        stage(ti, sp2, 0); stage(ti, sp2, 1);
      }

      { // compute sp s from this wave's kg-tile
        const char* As = lds + ((2 * s + kg) % 6) * 8192;
        const int fb = ((s >> 2) ? 16 : 0) + (s & 3) * 4;
#pragma unroll
        for (int kk = 0; kk < 4; ++kk) {
#pragma unroll
          for (int mi = 0; mi < 2; ++mi) {
            int r = mi * 32 + (lane & 31);
            f16x8 a = *(const f16x8*)(As + r * 128 +
                        ((kk * 32 + (lane >> 5) * 16) ^ ((r & 7) << 4)));
            acc[mi] = __builtin_amdgcn_mfma_f32_32x32x16_f16(
                a, bfrag[fb + kk], acc[mi], 0, 0, 0);
          }
        }
      }
    }

    // ---- epilogue: kg-reduce + gate-gather via LDS, cell, m-store ----------
    {
      float* w = accf + wid * 2048;           // SoA: [reg 0..31][lane]
#pragma unroll
      for (int mi = 0; mi < 2; ++mi)
#pragma unroll
        for (int rg = 0; rg < 16; ++rg)
          w[(mi * 16 + rg) * 64 + lane] = acc[mi][rg];
    }
    __syncthreads();
    {
      f16* mho = MHb + (size_t)((t & 1) ^ 1) * 262144;
      f16* mlo = MLb + (size_t)((t & 1) ^ 1) * 262144;
#pragma unroll
      for (int pp = 0; pp < 2; ++pp) {
        int pi   = pp * 512 + tid;            // fixed (b,h) ownership
        int bloc = pi >> 4, hl = pi & 15;
        int rl = bloc & 31, mi = bloc >> 5;
        int q0 = mi * 16 + ((rl >> 3) << 2) + (rl & 3);
        int lhalf = ((rl >> 2) & 1) << 5;
        int nw = hl >> 2, cb = hl & 3;
        float s0v, s1v, s2v, s3v, s4v, s5v, s6v, s7v;
        {
          int o;
          o = q0 * 64 + lhalf + 0 * 4 + cb; s0v = accf[nw*2048 + o] + accf[(4+nw)*2048 + o];
          o = q0 * 64 + lhalf + 1 * 4 + cb; s1v = accf[nw*2048 + o] + accf[(4+nw)*2048 + o];
          o = q0 * 64 + lhalf + 2 * 4 + cb; s2v = accf[nw*2048 + o] + accf[(4+nw)*2048 + o];
          o = q0 * 64 + lhalf + 3 * 4 + cb; s3v = accf[nw*2048 + o] + accf[(4+nw)*2048 + o];
          o = q0 * 64 + lhalf + 4 * 4 + cb; s4v = accf[nw*2048 + o] + accf[(4+nw)*2048 + o];
          o = q0 * 64 + lhalf + 5 * 4 + cb; s5v = accf[nw*2048 + o] + accf[(4+nw)*2048 + o];
          o = q0 * 64 + lhalf + 6 * 4 + cb; s6v = accf[nw*2048 + o] + accf[(4+nw)*2048 + o];
          o = q0 * 64 + lhalf + 7 * 4 + cb; s7v = accf[nw*2048 + o] + accf[(4+nw)*2048 + o];
        }
        float l10 = sigm_f(s0v);
        float l11 = fmaxf(s1v, 0.f);
        float l12 = sigm_f(s2v);
        float l13 = fmaxf(s3v, 0.f);
        float l14 = tanh_f(s4v);
        float l15 = sigm_f(s5v);
        float l16 = tanh_f(s6v);
        float l17 = sigm_f(s7v);
        float l20 = tanh_f(l10 * l11);
        float l21 = tanh_f(l12 + l13);
        float l22 = tanh_f(l14 * l15);
        float l23 = sigm_f(l16 + l17);
        float cn  = tanh_f(l20 + creg[pp]) * l21;
        float l31 = tanh_f(l22 + l23);
        float mn  = tanh_f(cn * l31);
        creg[pp] = cn;
        int b = mt * 64 + bloc, h = nt * 16 + hl;
        size_t idx = ((size_t)b << 9) + h;
        f16 mhv = (f16)mn;
        mho[idx] = mhv;
        mlo[idx] = (f16)(mn - (float)mhv);
        if (t == SEQ - 1) out[idx] = mn;
      }
    }

    if (t < SEQ - 1) {
      __builtin_amdgcn_fence(__ATOMIC_RELEASE, "agent");   // drain + wb stores
      __builtin_amdgcn_s_barrier();
      if (tid == 0)
        __hip_atomic_fetch_add(bar, 1u, __ATOMIC_RELAXED, __HIP_MEMORY_SCOPE_AGENT);
    }
  }
  asm volatile("s_waitcnt vmcnt(0)" ::: "memory");
}

// ---- tier 3: proven per-step kernel ---------------------------------------
__global__ __launch_bounds__(256)
void nas_step(const f16* __restrict__ xt, const f16* __restrict__ bt,
              const f16* __restrict__ mh_in, const f16* __restrict__ ml_in,
              f16* __restrict__ mh_out, f16* __restrict__ ml_out,
              float* __restrict__ cst, float* __restrict__ out, int last) {
  __shared__ char lds[49152];
  char* Abase = lds;
  char* Bbase = lds + 16384;
  const int tid  = threadIdx.x;
  const int lane = tid & 63;
  const int wid  = tid >> 6;
  const int nt   = blockIdx.x;
  const int mt   = blockIdx.y;
  const f16* asrc[3] = { xt, mh_in, ml_in };

  auto stageA = [&](int buf, int kt) {
    const f16* src = asrc[kt >> 3];
    int kofs = (kt & 7) * 64;
#pragma unroll
    for (int p = 0; p < 2; ++p) {
      int u = p * 256 + tid; int r = u >> 3; int c16 = (u & 7) ^ (r & 7);
      gll16(src + ((size_t)(mt * 64 + r) << 9) + kofs + c16 * 8,
            Abase + buf * 8192 + (p * 256 + wid * 64) * 16);
    }
  };
  auto stageB = [&](int buf, int kt) {
    int kg2 = (kt < 8) ? (kt << 6) : (512 + ((kt & 7) << 6));
#pragma unroll
    for (int p = 0; p < 4; ++p) {
      int u = p * 256 + tid; int r = u >> 3; int c16 = (u & 7) ^ (r & 7);
      gll16(bt + (size_t)(nt * 128 + r) * 1024 + kg2 + c16 * 8,
            Bbase + buf * 16384 + (p * 256 + wid * 64) * 16);
    }
  };

  f32x4 acc[8];
#pragma unroll
  for (int i = 0; i < 8; ++i) acc[i] = (f32x4){0.f, 0.f, 0.f, 0.f};

  stageA(0, 0); stageB(0, 0);
  __syncthreads();
  for (int kt = 0; kt < NKT; ++kt) {
    int cur = kt & 1;
    if (kt + 1 < NKT) { stageA(cur ^ 1, kt + 1); stageB(cur ^ 1, kt + 1); }
    const char* At = Abase + cur * 8192;
    const char* Bt = Bbase + cur * 16384;
#pragma unroll
    for (int kk = 0; kk < 2; ++kk) {
      int cbv = (kk * 32 + ((lane >> 4) << 3)) * 2;
      int ra = wid * 16 + (lane & 15);
      f16x8 a = *(const f16x8*)(At + ra * 128 + (cbv ^ ((ra & 7) << 4)));
#pragma unroll
      for (int ni2 = 0; ni2 < 8; ++ni2) {
        int rb = ni2 * 16 + (lane & 15);
        f16x8 b = *(const f16x8*)(Bt + rb * 128 + (cbv ^ ((rb & 7) << 4)));
        acc[ni2] = __builtin_amdgcn_mfma_f32_16x16x32_f16(a, b, acc[ni2], 0, 0, 0);
      }
    }
    __syncthreads();
  }

  const int h = nt * 16 + (lane & 15);
  const int rb4 = (lane >> 4) << 2;
#pragma unroll
  for (int q = 0; q < 4; ++q) {
    int b = mt * 64 + wid * 16 + rb4 + q;
    size_t idx = ((size_t)b << 9) + h;
    float l10 = sigm_f(acc[0][q]);
    float l11 = fmaxf(acc[1][q], 0.f);
    float l12 = sigm_f(acc[2][q]);
    float l13 = fmaxf(acc[3][q], 0.f);
    float l14 = tanh_f(acc[4][q]);
    float l15 = sigm_f(acc[5][q]);
    float l16 = tanh_f(acc[6][q]);
    float l17 = sigm_f(acc[7][q]);
    float l20 = tanh_f(l10 * l11);
    float l21 = tanh_f(l12 + l13);
    float l22 = tanh_f(l14 * l15);
    float l23 = sigm_f(l16 + l17);
    float cn  = tanh_f(l20 + cst[idx]) * l21;
    float l31 = tanh_f(l22 + l23);
    float mn  = tanh_f(cn * l31);
    cst[idx] = cn;
    f16 mhv = (f16)mn;
    mh_out[idx] = mhv;
    ml_out[idx] = (f16)(mn - (float)mhv);
    if (last) out[idx] = mn;
  }
}

// ---- host -----------------------------------------------------------------
extern "C" void kernel_launch(void* const* d_in, const int* in_sizes, int n_in,
                              void* d_out, int out_size, void* d_ws, size_t ws_size,
                              hipStream_t stream) {
  const float* inputs = (const float*)d_in[0];
  const float* wih    = (const float*)d_in[1];
  const float* whh    = (const float*)d_in[2];
  float* out = (float*)d_out;
  char* ws   = (char*)d_ws;

  f16*          BTp = (f16*)(ws + OFF_BT);
  f16*          Xp  = (f16*)(ws + OFF_X16);
  f16*          MHp = (f16*)(ws + OFF_MH);
  f16*          MLp = (f16*)(ws + OFF_ML);
  float*        Cp  = (float*)(ws + OFF_C);
  unsigned int* bp  = (unsigned int*)(ws + OFF_BAR);

  build_bt<<<4096, 256, 0, stream>>>(wih, whh, BTp);
  cvt_x<<<2048, 256, 0, stream>>>((const float4*)inputs, Xp, SEQ * B_ * 512 / 4);
  init_state<<<1024, 256, 0, stream>>>(MHp, MLp, Cp, bp);

  void* args[] = { (void*)&Xp, (void*)&BTp, (void*)&MHp, (void*)&MLp,
                   (void*)&bp, (void*)&out };
  hipError_t ce = hipLaunchCooperativeKernel((const void*)nas_persist2, dim3(256),
                                             dim3(512), args, 0, stream);
  if (ce != hipSuccess) {
    (void)hipGetLastError();
    nas_persist2<<<dim3(256), dim3(512), 0, stream>>>(Xp, BTp, MHp, MLp, bp, out);
    if (hipGetLastError() != hipSuccess) {
      for (int t = 0; t < SEQ; ++t) {
        int cur = t & 1;
        nas_step<<<dim3(32, 8), 256, 0, stream>>>(
            Xp + (size_t)t * B_ * 512, BTp,
            MHp + (size_t)cur * 262144, MLp + (size_t)cur * 262144,
            MHp + (size_t)(cur ^ 1) * 262144, MLp + (size_t)(cur ^ 1) * 262144,
            Cp, out, (t == SEQ - 1) ? 1 : 0);
      }
    }
  }
}

// Round 5
// 4080.086 us; speedup vs baseline: 1.4939x; 1.4939x over previous
//
#include <hip/hip_runtime.h>

#define SEQ  128
#define B_   512
#define NKT  24

typedef _Float16 f16;
typedef _Float16 f16x8 __attribute__((ext_vector_type(8)));
typedef float    f32x4  __attribute__((ext_vector_type(4)));
typedef float    f32x16 __attribute__((ext_vector_type(16)));

// ws layout (bytes)
#define OFF_BT   0u          // [4096][1024] f16 (r<512: Wih, r>=512: Whh)
#define OFF_X16  8388608u    // [128][512][512] f16
#define OFF_MH   75497472u   // [2][262144] f16
#define OFF_ML   76546048u   // [2][262144] f16
#define OFF_C    77594624u   // [512][512] f32 (tier-3 only)
#define OFF_BAR  78643200u   // u32 arrival counter

__device__ __forceinline__ void gll16(const void* g, void* l) {
  __builtin_amdgcn_global_load_lds(
      (const __attribute__((address_space(1))) unsigned int*)g,
      (__attribute__((address_space(3))) unsigned int*)l, 16, 0, 0);
}
__device__ __forceinline__ float sigm_f(float x) {
  return __fdividef(1.f, 1.f + __expf(-x));
}
__device__ __forceinline__ float tanh_f(float x) {
  x = fminf(fmaxf(x, -15.f), 15.f);
  float u = __expf(2.f * x);
  return __fdividef(u - 1.f, u + 1.f);
}
#define VW(n) asm volatile("s_waitcnt vmcnt(" #n ")" ::: "memory")

// ---- one-time prep --------------------------------------------------------
__global__ void build_bt(const float* __restrict__ wih,
                         const float* __restrict__ whh,
                         f16* __restrict__ bt) {
  int n  = blockIdx.x;                 // n = ht*128 + gate*16 + hl
  int hl = n & 15, k = (n >> 4) & 7, ht = n >> 7;
  int h  = ht * 16 + hl;
  const float* pih = wih + (size_t)k * 512 * 512 + h;
  const float* phh = whh + (size_t)k * 512 * 512 + h;
  f16* dst = bt + (size_t)n * 1024;
  for (int r = threadIdx.x; r < 512; r += 256) {
    dst[r]       = (f16)pih[(size_t)r * 512];
    dst[512 + r] = (f16)phh[(size_t)r * 512];
  }
}

__global__ void cvt_x(const float4* __restrict__ x, f16* __restrict__ y, int nvec) {
  typedef _Float16 f16x4v __attribute__((ext_vector_type(4)));
  int i = blockIdx.x * blockDim.x + threadIdx.x;
  int stride = gridDim.x * blockDim.x;
  f16x4v* yo = (f16x4v*)y;
  for (; i < nvec; i += stride) {
    float4 v = x[i];
    f16x4v o = { (f16)v.x, (f16)v.y, (f16)v.z, (f16)v.w };
    yo[i] = o;
  }
}

__global__ void init_state(f16* __restrict__ mh, f16* __restrict__ ml,
                           float* __restrict__ c, unsigned int* __restrict__ bar) {
  int i = blockIdx.x * blockDim.x + threadIdx.x;
  mh[i] = (f16)1.f;
  ml[i] = (f16)0.f;
  c[i]  = 1.f;
  if (i == 0) *bar = 0u;
}

// ---- tier 1/2: persistent, B-in-registers (macro-unrolled superphases) ----
// grid 256 (nt = bid&31, mt = bid>>5), 512 threads = 8 waves.
// wid: kg = wid>>2 (K-half of each 128-K block), ni = wid&3 (32 N-cols).
// Wave tile 64Mx32N via 2x mfma_32x32x16. bfrag[32] = 128 VGPR, loaded once.
// 12 superphases/step: s=0..3 x, 4..7 mh, 8..11 ml (reuse Whh frags).
// A-tiles [64M][128K] f16 (16KB), 4-slot ring, staged 2 sps ahead, VW(2).
// 16-slot XOR swizzle (256B rows): 32-row fragment reads are 2-way (free).
__global__ __launch_bounds__(512, 2)
void nas_persist3(const f16* __restrict__ X, const f16* __restrict__ BT,
                  f16* __restrict__ MHb, f16* __restrict__ MLb,
                  unsigned int* __restrict__ bar, float* __restrict__ out) {
  __shared__ char lds[139264];               // 4x16KB ring | 73728B acc buffer
  float* accf = (float*)(lds + 65536);
  const int tid  = threadIdx.x;
  const int lane = tid & 63;
  const int wid  = tid >> 6;
  const int kg   = wid >> 2;
  const int ni   = wid & 3;
  const int nt   = blockIdx.x & 31;
  const int mt   = blockIdx.x >> 5;

  // B prologue: col c=lane&31 -> n = nt*128 + (c>>2)*16 + ni*4 + (c&3)
  f16x8 bfrag[32];
  {
    int c = lane & 31;
    int nrow = nt * 128 + (c >> 2) * 16 + ni * 4 + (c & 3);
    const f16* bb = BT + (size_t)nrow * 1024 + kg * 64 + (lane >> 5) * 8;
#pragma unroll
    for (int f = 0; f < 16; ++f)             // Wih: f = jj*4 + kk
      bfrag[f] = *(const f16x8*)(bb + (f >> 2) * 128 + (f & 3) * 16);
#pragma unroll
    for (int f = 0; f < 16; ++f)             // Whh (shared by mh and ml)
      bfrag[16 + f] = *(const f16x8*)(bb + 512 + (f >> 2) * 128 + (f & 3) * 16);
  }

  // stage superphase spe of step ti: one [64][128K] tile, 2 gll16/thread.
  // logical (r, c-chunk) at phys r*256 + 16*(c ^ (r&15)) via swizzled source.
  auto stage = [&](int ti, int spe) {
    int src = spe >> 2, jj = spe & 3;
    const f16* base = (src == 0) ? X + (size_t)ti * 262144
                    : (src == 1) ? MHb + (size_t)(ti & 1) * 262144
                                 : MLb + (size_t)(ti & 1) * 262144;
    char* slotb = lds + (spe & 3) * 16384;
#pragma unroll
    for (int j = 0; j < 2; ++j) {
      int u = j * 512 + tid;
      int r = u >> 4, c = u & 15;
      int cs = c ^ (r & 15);
      gll16(base + ((size_t)(mt * 64 + r) << 9) + jj * 128 + cs * 8,
            slotb + (j * 512 + wid * 64) * 16);
    }
  };

  f32x16 acc[2];
  float creg[2];
  creg[0] = 1.f; creg[1] = 1.f;

  stage(0, 0); stage(0, 1);                  // prologue

#define SP(s_) do {                                                          \
    VW(2);                                                                   \
    __builtin_amdgcn_s_barrier();                                            \
    asm volatile("" ::: "memory");                                           \
    if ((s_) == 2 && t > 0) {                                                \
      if (tid == 0) {                                                        \
        while (__hip_atomic_load(bar, __ATOMIC_RELAXED,                      \
                                 __HIP_MEMORY_SCOPE_AGENT) < (unsigned)(256u * t)) \
          __builtin_amdgcn_s_sleep(2);                                       \
        __builtin_amdgcn_fence(__ATOMIC_ACQUIRE, "agent");                   \
      }                                                                      \
      __builtin_amdgcn_s_barrier();                                          \
    }                                                                        \
    { int sp2 = (s_) + 2, ti = t;                                            \
      if (sp2 >= 12) { sp2 -= 12; ti = (t + 1 < SEQ) ? t + 1 : t; }          \
      stage(ti, sp2); }                                                      \
    { const char* As = lds + ((s_) & 3) * 16384;                             \
      constexpr int fb = ((s_) < 4) ? (s_) * 4 : 16 + ((s_) & 3) * 4;        \
      _Pragma("unroll")                                                      \
      for (int kk = 0; kk < 4; ++kk) {                                       \
        _Pragma("unroll")                                                    \
        for (int mi = 0; mi < 2; ++mi) {                                     \
          int r = mi * 32 + (lane & 31);                                     \
          int ch = kg * 8 + kk * 2 + (lane >> 5);                            \
          f16x8 a = *(const f16x8*)(As + r * 256 + ((ch ^ (r & 15)) << 4));  \
          acc[mi] = __builtin_amdgcn_mfma_f32_32x32x16_f16(                  \
              a, bfrag[fb + kk], acc[mi], 0, 0, 0);                          \
        } } }                                                                \
  } while (0)

  for (int t = 0; t < SEQ; ++t) {
#pragma unroll
    for (int mi = 0; mi < 2; ++mi) {
      f32x16 z = {0.f,0.f,0.f,0.f,0.f,0.f,0.f,0.f,
                  0.f,0.f,0.f,0.f,0.f,0.f,0.f,0.f};
      acc[mi] = z;
    }

    SP(0); SP(1); SP(2); SP(3); SP(4); SP(5);
    SP(6); SP(7); SP(8); SP(9); SP(10); SP(11);

    // ---- epilogue ---------------------------------------------------------
    // write: value (W = ni*2+kg, R = mi*16+rg, lane) at
    //   accf[R*576 + W*72 + (lane ^ ((R&7)<<2))]  — 2-way max on both sides
#pragma unroll
    for (int mi = 0; mi < 2; ++mi)
#pragma unroll
      for (int rg = 0; rg < 16; ++rg) {
        int R = mi * 16 + rg;
        accf[R * 576 + (ni * 2 + kg) * 72 + (lane ^ ((R & 7) << 2))] = acc[mi][rg];
      }
    __syncthreads();
    {
      f16* mho = MHb + (size_t)((t & 1) ^ 1) * 262144;
      f16* mlo = MLb + (size_t)((t & 1) ^ 1) * 262144;
#pragma unroll
      for (int pp = 0; pp < 2; ++pp) {
        int pi   = pp * 512 + tid;            // fixed (b,h) ownership
        int bloc = pi >> 4, hl = pi & 15;
        int mi = bloc >> 5, rl = bloc & 31;
        int R  = mi * 16 + ((rl >> 3) << 2) + (rl & 3);
        int Lb = (((rl >> 2) & 1) << 5) | (hl & 3);
        int nw = hl >> 2;
        int xr = (R & 7) << 2;
        int ab = R * 576 + nw * 144;
        float gv[8];
#pragma unroll
        for (int gi = 0; gi < 8; ++gi) {
          int a0 = ab + ((Lb | (gi << 2)) ^ xr);
          gv[gi] = accf[a0] + accf[a0 + 72];  // kg=0 + kg=1
        }
        float l10 = sigm_f(gv[0]);
        float l11 = fmaxf(gv[1], 0.f);
        float l12 = sigm_f(gv[2]);
        float l13 = fmaxf(gv[3], 0.f);
        float l14 = tanh_f(gv[4]);
        float l15 = sigm_f(gv[5]);
        float l16 = tanh_f(gv[6]);
        float l17 = sigm_f(gv[7]);
        float l20 = tanh_f(l10 * l11);
        float l21 = tanh_f(l12 + l13);
        float l22 = tanh_f(l14 * l15);
        float l23 = sigm_f(l16 + l17);
        float cn  = tanh_f(l20 + creg[pp]) * l21;
        float l31 = tanh_f(l22 + l23);
        float mn  = tanh_f(cn * l31);
        creg[pp] = cn;
        int b = mt * 64 + bloc, h = nt * 16 + hl;
        size_t idx = ((size_t)b << 9) + h;
        f16 mhv = (f16)mn;
        mho[idx] = mhv;
        mlo[idx] = (f16)(mn - (float)mhv);
        if (t == SEQ - 1) out[idx] = mn;
      }
    }
    __syncthreads();                          // accf reads done before reuse

    if (t < SEQ - 1) {
      __builtin_amdgcn_fence(__ATOMIC_RELEASE, "agent");   // drain + wb
      __builtin_amdgcn_s_barrier();
      if (tid == 0)
        __hip_atomic_fetch_add(bar, 1u, __ATOMIC_RELAXED, __HIP_MEMORY_SCOPE_AGENT);
    }
  }
  asm volatile("s_waitcnt vmcnt(0)" ::: "memory");
#undef SP
}

// ---- tier 3: proven per-step kernel ---------------------------------------
__global__ __launch_bounds__(256)
void nas_step(const f16* __restrict__ xt, const f16* __restrict__ bt,
              const f16* __restrict__ mh_in, const f16* __restrict__ ml_in,
              f16* __restrict__ mh_out, f16* __restrict__ ml_out,
              float* __restrict__ cst, float* __restrict__ out, int last) {
  __shared__ char lds[49152];
  char* Abase = lds;
  char* Bbase = lds + 16384;
  const int tid  = threadIdx.x;
  const int lane = tid & 63;
  const int wid  = tid >> 6;
  const int nt   = blockIdx.x;
  const int mt   = blockIdx.y;
  const f16* asrc[3] = { xt, mh_in, ml_in };

  auto stageA = [&](int buf, int kt) {
    const f16* src = asrc[kt >> 3];
    int kofs = (kt & 7) * 64;
#pragma unroll
    for (int p = 0; p < 2; ++p) {
      int u = p * 256 + tid; int r = u >> 3; int c16 = (u & 7) ^ (r & 7);
      gll16(src + ((size_t)(mt * 64 + r) << 9) + kofs + c16 * 8,
            Abase + buf * 8192 + (p * 256 + wid * 64) * 16);
    }
  };
  auto stageB = [&](int buf, int kt) {
    int kg2 = (kt < 8) ? (kt << 6) : (512 + ((kt & 7) << 6));
#pragma unroll
    for (int p = 0; p < 4; ++p) {
      int u = p * 256 + tid; int r = u >> 3; int c16 = (u & 7) ^ (r & 7);
      gll16(bt + (size_t)(nt * 128 + r) * 1024 + kg2 + c16 * 8,
            Bbase + buf * 16384 + (p * 256 + wid * 64) * 16);
    }
  };

  f32x4 acc[8];
#pragma unroll
  for (int i = 0; i < 8; ++i) acc[i] = (f32x4){0.f, 0.f, 0.f, 0.f};

  stageA(0, 0); stageB(0, 0);
  __syncthreads();
  for (int kt = 0; kt < NKT; ++kt) {
    int cur = kt & 1;
    if (kt + 1 < NKT) { stageA(cur ^ 1, kt + 1); stageB(cur ^ 1, kt + 1); }
    const char* At = Abase + cur * 8192;
    const char* Bt = Bbase + cur * 16384;
#pragma unroll
    for (int kk = 0; kk < 2; ++kk) {
      int cbv = (kk * 32 + ((lane >> 4) << 3)) * 2;
      int ra = wid * 16 + (lane & 15);
      f16x8 a = *(const f16x8*)(At + ra * 128 + (cbv ^ ((ra & 7) << 4)));
#pragma unroll
      for (int ni2 = 0; ni2 < 8; ++ni2) {
        int rb = ni2 * 16 + (lane & 15);
        f16x8 b = *(const f16x8*)(Bt + rb * 128 + (cbv ^ ((rb & 7) << 4)));
        acc[ni2] = __builtin_amdgcn_mfma_f32_16x16x32_f16(a, b, acc[ni2], 0, 0, 0);
      }
    }
    __syncthreads();
  }

  const int h = nt * 16 + (lane & 15);
  const int rb4 = (lane >> 4) << 2;
#pragma unroll
  for (int q = 0; q < 4; ++q) {
    int b = mt * 64 + wid * 16 + rb4 + q;
    size_t idx = ((size_t)b << 9) + h;
    float l10 = sigm_f(acc[0][q]);
    float l11 = fmaxf(acc[1][q], 0.f);
    float l12 = sigm_f(acc[2][q]);
    float l13 = fmaxf(acc[3][q], 0.f);
    float l14 = tanh_f(acc[4][q]);
    float l15 = sigm_f(acc[5][q]);
    float l16 = tanh_f(acc[6][q]);
    float l17 = sigm_f(acc[7][q]);
    float l20 = tanh_f(l10 * l11);
    float l21 = tanh_f(l12 + l13);
    float l22 = tanh_f(l14 * l15);
    float l23 = sigm_f(l16 + l17);
    float cn  = tanh_f(l20 + cst[idx]) * l21;
    float l31 = tanh_f(l22 + l23);
    float mn  = tanh_f(cn * l31);
    cst[idx] = cn;
    f16 mhv = (f16)mn;
    mh_out[idx] = mhv;
    ml_out[idx] = (f16)(mn - (float)mhv);
    if (last) out[idx] = mn;
  }
}

// ---- host -----------------------------------------------------------------
extern "C" void kernel_launch(void* const* d_in, const int* in_sizes, int n_in,
                              void* d_out, int out_size, void* d_ws, size_t ws_size,
                              hipStream_t stream) {
  const float* inputs = (const float*)d_in[0];
  const float* wih    = (const float*)d_in[1];
  const float* whh    = (const float*)d_in[2];
  float* out = (float*)d_out;
  char* ws   = (char*)d_ws;

  f16*          BTp = (f16*)(ws + OFF_BT);
  f16*          Xp  = (f16*)(ws + OFF_X16);
  f16*          MHp = (f16*)(ws + OFF_MH);
  f16*          MLp = (f16*)(ws + OFF_ML);
  float*        Cp  = (float*)(ws + OFF_C);
  unsigned int* bp  = (unsigned int*)(ws + OFF_BAR);

  build_bt<<<4096, 256, 0, stream>>>(wih, whh, BTp);
  cvt_x<<<2048, 256, 0, stream>>>((const float4*)inputs, Xp, SEQ * B_ * 512 / 4);
  init_state<<<1024, 256, 0, stream>>>(MHp, MLp, Cp, bp);

  void* args[] = { (void*)&Xp, (void*)&BTp, (void*)&MHp, (void*)&MLp,
                   (void*)&bp, (void*)&out };
  hipError_t ce = hipLaunchCooperativeKernel((const void*)nas_persist3, dim3(256),
                                             dim3(512), args, 0, stream);
  if (ce != hipSuccess) {
    (void)hipGetLastError();
    nas_persist3<<<dim3(256), dim3(512), 0, stream>>>(Xp, BTp, MHp, MLp, bp, out);
    if (hipGetLastError() != hipSuccess) {
      for (int t = 0; t < SEQ; ++t) {
        int cur = t & 1;
        nas_step<<<dim3(32, 8), 256, 0, stream>>>(
            Xp + (size_t)t * B_ * 512, BTp,
            MHp + (size_t)cur * 262144, MLp + (size_t)cur * 262144,
            MHp + (size_t)(cur ^ 1) * 262144, MLp + (size_t)(cur ^ 1) * 262144,
            Cp, out, (t == SEQ - 1) ? 1 : 0);
      }
    }
  }
}